// Round 6
// baseline (270.927 us; speedup 1.0000x reference)
//
#include <hip/hip_runtime.h>
#include <math.h>

#define B_   32
#define N_   128
#define H_   100
#define ROWS (B_ * N_)    // 4096
#define RH   (ROWS * H_)  // 409600
#define OUTSZ (B_ * H_)   // 3200

// ---------------------------------------------------------------------------
// K1: hw = nodes@Ww ONLY (initial hv computed in-register by pass 1).
// Also zero-initializes out. (unchanged from the 192us baseline)
__global__ __launch_bounds__(256, 6) void k_proj0(const float* __restrict__ nodes,
                                                  const float* __restrict__ Ww,
                                                  float* __restrict__ hw,
                                                  float* __restrict__ out) {
    __shared__ float nod_s[2][H_];
    const int row0 = blockIdx.x * 2;
    const int t = threadIdx.x, r = t >> 7, j = t & 127;
    {   // zero out[] (3 dispatches before any atomicAdd; stream-ordered)
        const int gid = blockIdx.x * 256 + t;
        if (gid < OUTSZ) out[gid] = 0.f;
    }
    {
        const float4* ng = (const float4*)(nodes + (size_t)row0 * H_);
        if (t < 50) ((float4*)nod_s)[t] = ng[t];
    }
    __syncthreads();
    if (j >= H_) return;
    const float4* h4p = (const float4*)nod_s[r];
    float wa = 0.f;
#pragma unroll 5
    for (int k4 = 0; k4 < 25; ++k4) {
        const float4 h4 = h4p[k4];
        const int k = k4 * 4;
        wa = fmaf(h4.x, Ww[(k + 0) * H_ + j], wa);
        wa = fmaf(h4.y, Ww[(k + 1) * H_ + j], wa);
        wa = fmaf(h4.z, Ww[(k + 2) * H_ + j], wa);
        wa = fmaf(h4.w, Ww[(k + 3) * H_ + j], wa);
    }
    hw[(size_t)(row0 + r) * H_ + j] = wa;
}

// ---------------------------------------------------------------------------
// K2 (r6): r5 geometry exactly; message loop restructured against CONVOY
// stalls. Cross-round invariant (r0-r5): VALU issue time is ~21-22 us in
// EVERY variant (VALUBusy x dur), stall X ~30 us survives relocating hww/
// weights/e across global/LDS/scalar -> no single operand stream is X.
// Hypothesis: waves leave the barrier in lockstep, issue identical 8-load
// batches to identical addresses (co-resident blocks share batch b), then
// all s_waitcnt together -> correlated stalls, burst congestion, no wave
// left to cover latency. VGPR=32 capped in-flight loads at ~8.
// Fix: (1) preload a full 32-w chunk of hww into registers (32 loads in
// flight; launch_bounds(256,6) gives ~85 VGPR headroom); (2) stagger chunk
// order per wave AND per block (rot = (wv+bx)&3) so co-resident waves
// stream different quarters of hw/edges simultaneously (fp-reorder only).
template <int MODE, int INIT_HV>
__global__ __launch_bounds__(256, 6) void k_pass(const float* __restrict__ edges,
                                                 const float* __restrict__ We,
                                                 const float* __restrict__ Wu,
                                                 const float* __restrict__ Wv,
                                                 const float* __restrict__ Ww,
                                                 const float* __restrict__ Wr,
                                                 const float* __restrict__ nodes,
                                                 float* __restrict__ hv_io,
                                                 const float* __restrict__ hw_in,
                                                 float* __restrict__ hw_out,
                                                 const float* __restrict__ hid_in,
                                                 float* __restrict__ hidden,
                                                 float* __restrict__ out) {
    __shared__ float  asum_part[4];        // per-wave partial row sums
    __shared__ unsigned qmask_s[2][4];     // per-row edge-mask bits (4x32)
    __shared__ float  hid_s[2][H_];
    __shared__ float  msg_s[2][H_];
    __shared__ float  hn_s[2][H_];
    __shared__ float  nod_s[2][H_];        // MODE 2 only
    __shared__ float  red_s[2][H_];        // MODE 2 only

    // batch-affine swizzle: co-resident blocks (≡ mod 256) share batch b
    const int bx = blockIdx.x;
    const int cu = bx & 255, slot = bx >> 8;
    const int b = cu >> 3;
    const int vt = (cu & 7) + slot * 8;
    const int row0 = b * N_ + vt * 2;

    const int t = threadIdx.x, r = t >> 7, j = t & 127;
    const int wv = t >> 6, lane = t & 63;
    const int row = row0 + r;
    const bool act = (j < H_);

    {   // ballot edge-mask bits + row sums
        const float4* eg = (const float4*)(edges + (size_t)row0 * N_ * 4);
        const float4 e = eg[t];                   // t == r*128 + j, coalesced
        float s = (e.x + e.y) + (e.z + e.w);
        const unsigned long long bal = __ballot(s != 0.f);
        if (lane == 0) {
            qmask_s[wv >> 1][(wv & 1) * 2]     = (unsigned)bal;
            qmask_s[wv >> 1][(wv & 1) * 2 + 1] = (unsigned)(bal >> 32);
        }
#pragma unroll
        for (int off = 32; off > 0; off >>= 1) s += __shfl_down(s, off);
        if (lane == 0) asum_part[wv] = s;
    }
    {   // stage pre-update hidden rows (50 float4); nodes too if readout pass
        const float4* hg = (const float4*)(hid_in + (size_t)row0 * H_);
        if (t < 50) ((float4*)hid_s)[t] = hg[t];
        if (MODE == 2) {
            const float4* ng = (const float4*)(nodes + (size_t)row0 * H_);
            if (t < 50) ((float4*)nod_s)[t] = ng[t];
        }
    }
    __syncthreads();

    const float nm = ((asum_part[2 * r] + asum_part[2 * r + 1]) != 0.f) ? 1.f : 0.f;

    if (act) {
        float hvv;
        if (INIT_HV) {      // pass 1: hv = hid @ Wv computed in-register
            const float4* h4p = (const float4*)hid_s[r];
            float va = 0.f;
#pragma unroll 5
            for (int k4 = 0; k4 < 25; ++k4) {
                const float4 h4 = h4p[k4];
                const int k = k4 * 4;
                va = fmaf(h4.x, Wv[(k + 0) * H_ + j], va);
                va = fmaf(h4.y, Wv[(k + 1) * H_ + j], va);
                va = fmaf(h4.z, Wv[(k + 2) * H_ + j], va);
                va = fmaf(h4.w, Wv[(k + 3) * H_ + j], va);
            }
            hvv = va;
        } else {
            hvv = hv_io[(size_t)row * H_ + j];
        }
        const float we0 = We[0 * H_ + j], we1 = We[1 * H_ + j];
        const float we2 = We[2 * H_ + j], we3 = We[3 * H_ + j];
        const float* hwp = hw_in + (size_t)b * N_ * H_ + j;

        // wave-uniform edge row pointer -> scalar (SMEM) loads
        const int rowu = __builtin_amdgcn_readfirstlane(row);
        const float4* erow = (const float4*)(edges + (size_t)rowu * N_ * 4);

        // wave+block staggered chunk order: desync co-resident streams
        const int rot = (wv + bx) & 3;

        float acc = 0.f;
        for (int ci = 0; ci < 4; ++ci) {          // 4 chunks of 32 w
            const int c = (ci + rot) & 3;         // wave-uniform
            const unsigned mq =
                __builtin_amdgcn_readfirstlane(qmask_s[r][c]);  // SGPR, uniform
            const float4* ec = erow + c * 32;
            const float*  hc = hwp + (size_t)(c * 32) * H_;
            // preload the whole chunk: 32 loads in flight
            float hbuf[32];
#pragma unroll
            for (int w8 = 0; w8 < 32; ++w8) hbuf[w8] = hc[w8 * H_];
#pragma unroll
            for (int w8 = 0; w8 < 32; ++w8) {
                const float4 e = ec[w8];          // s_load_dwordx4 (uniform)
                const float  m = ((mq >> w8) & 1u) ? 1.f : 0.f;  // SALU cselect
                float p = hvv + hbuf[w8];
                p = fmaf(e.x, we0, p);
                p = fmaf(e.y, we1, p);
                p = fmaf(e.z, we2, p);
                p = fmaf(e.w, we3, p);
                acc = fmaf(m, fmaxf(p, 0.f), acc);
            }
        }
        msg_s[r][j] = acc;
    }
    __syncthreads();

    if (act) {
        const float4* h4p = (const float4*)hid_s[r];
        const float4* m4p = (const float4*)msg_s[r];
        float u = 0.f;
#pragma unroll 5
        for (int k4 = 0; k4 < 25; ++k4) {
            const float4 h4 = h4p[k4];
            const int k = k4 * 4;
            u = fmaf(h4.x, Wu[(k + 0) * H_ + j], u);
            u = fmaf(h4.y, Wu[(k + 1) * H_ + j], u);
            u = fmaf(h4.z, Wu[(k + 2) * H_ + j], u);
            u = fmaf(h4.w, Wu[(k + 3) * H_ + j], u);
        }
#pragma unroll 5
        for (int k4 = 0; k4 < 25; ++k4) {
            const float4 m4 = m4p[k4];
            const int k = H_ + k4 * 4;
            u = fmaf(m4.x, Wu[(k + 0) * H_ + j], u);
            u = fmaf(m4.y, Wu[(k + 1) * H_ + j], u);
            u = fmaf(m4.z, Wu[(k + 2) * H_ + j], u);
            u = fmaf(m4.w, Wu[(k + 3) * H_ + j], u);
        }
        const float nh = (nm != 0.f) ? tanhf(u) : hid_s[r][j];
        hn_s[r][j] = nh;
        if (MODE == 1) hidden[(size_t)row * H_ + j] = nh;
    }
    __syncthreads();

    if (MODE == 1) {        // next pass's hv/hw from fresh hidden (own rows)
        if (act) {
            const float4* h4p = (const float4*)hn_s[r];
            float va = 0.f, wa = 0.f;
#pragma unroll 5
            for (int k4 = 0; k4 < 25; ++k4) {
                const float4 h4 = h4p[k4];
                const int k = k4 * 4;
                va = fmaf(h4.x, Wv[(k + 0) * H_ + j], va);
                wa = fmaf(h4.x, Ww[(k + 0) * H_ + j], wa);
                va = fmaf(h4.y, Wv[(k + 1) * H_ + j], va);
                wa = fmaf(h4.y, Ww[(k + 1) * H_ + j], wa);
                va = fmaf(h4.z, Wv[(k + 2) * H_ + j], va);
                wa = fmaf(h4.z, Ww[(k + 2) * H_ + j], wa);
                va = fmaf(h4.w, Wv[(k + 3) * H_ + j], va);
                wa = fmaf(h4.w, Ww[(k + 3) * H_ + j], wa);
            }
            hv_io[(size_t)row * H_ + j] = va;     // row-local: safe in-place
            hw_out[(size_t)row * H_ + j] = wa;    // double-buffered
        }
    } else {                // MODE 2: fused readout
        if (act) {
            const float4* h4p = (const float4*)hn_s[r];
            const float4* n4p = (const float4*)nod_s[r];
            float u = 0.f;
#pragma unroll 5
            for (int k4 = 0; k4 < 25; ++k4) {
                const float4 h4 = h4p[k4];
                const int k = k4 * 4;
                u = fmaf(h4.x, Wr[(k + 0) * H_ + j], u);
                u = fmaf(h4.y, Wr[(k + 1) * H_ + j], u);
                u = fmaf(h4.z, Wr[(k + 2) * H_ + j], u);
                u = fmaf(h4.w, Wr[(k + 3) * H_ + j], u);
            }
#pragma unroll 5
            for (int k4 = 0; k4 < 25; ++k4) {
                const float4 n4 = n4p[k4];
                const int k = H_ + k4 * 4;
                u = fmaf(n4.x, Wr[(k + 0) * H_ + j], u);
                u = fmaf(n4.y, Wr[(k + 1) * H_ + j], u);
                u = fmaf(n4.z, Wr[(k + 2) * H_ + j], u);
                u = fmaf(n4.w, Wr[(k + 3) * H_ + j], u);
            }
            red_s[r][j] = nm * fmaxf(u, 0.f);
        }
        __syncthreads();
        if (t < H_) atomicAdd(out + b * H_ + t, red_s[0][t] + red_s[1][t]);
    }
}

// ---------------------------------------------------------------------------
extern "C" void kernel_launch(void* const* d_in, const int* in_sizes, int n_in,
                              void* d_out, int out_size, void* d_ws, size_t ws_size,
                              hipStream_t stream) {
    const float* nodes = (const float*)d_in[0];
    const float* edges = (const float*)d_in[1];
    const float* Wv    = (const float*)d_in[2];
    const float* Ww    = (const float*)d_in[3];
    const float* We    = (const float*)d_in[4];
    const float* Wu    = (const float*)d_in[5];
    const float* Wr    = (const float*)d_in[6];
    float* out = (float*)d_out;

    float* hidden = (float*)d_ws;     // RH
    float* hv     = hidden + RH;      // RH
    float* hwA    = hv + RH;          // RH
    float* hwB    = hwA + RH;         // RH

    k_proj0<<<ROWS / 2, 256, 0, stream>>>(nodes, Ww, hwA, out);

    k_pass<1, 1><<<ROWS / 2, 256, 0, stream>>>(edges, We, Wu, Wv, Ww, Wr, nodes,
                                               hv, hwA, hwB, nodes, hidden, out);
    k_pass<1, 0><<<ROWS / 2, 256, 0, stream>>>(edges, We, Wu, Wv, Ww, Wr, nodes,
                                               hv, hwB, hwA, hidden, hidden, out);
    k_pass<2, 0><<<ROWS / 2, 256, 0, stream>>>(edges, We, Wu, Wv, Ww, Wr, nodes,
                                               hv, hwA, hwB, hidden, hidden, out);
}

// Round 7
// 226.913 us; speedup vs baseline: 1.1940x; 1.1940x over previous
//
#include <hip/hip_runtime.h>
#include <math.h>

#define B_   32
#define N_   128
#define H_   100
#define ROWS (B_ * N_)    // 4096
#define RH   (ROWS * H_)  // 409600
#define OUTSZ (B_ * H_)   // 3200

// ---------------------------------------------------------------------------
// K1: hw = nodes@Ww ONLY (initial hv computed in-register by pass 1).
// Also zero-initializes out. (unchanged from the 192us baseline)
__global__ __launch_bounds__(256, 6) void k_proj0(const float* __restrict__ nodes,
                                                  const float* __restrict__ Ww,
                                                  float* __restrict__ hw,
                                                  float* __restrict__ out) {
    __shared__ float nod_s[2][H_];
    const int row0 = blockIdx.x * 2;
    const int t = threadIdx.x, r = t >> 7, j = t & 127;
    {   // zero out[] (3 dispatches before any atomicAdd; stream-ordered)
        const int gid = blockIdx.x * 256 + t;
        if (gid < OUTSZ) out[gid] = 0.f;
    }
    {
        const float4* ng = (const float4*)(nodes + (size_t)row0 * H_);
        if (t < 50) ((float4*)nod_s)[t] = ng[t];
    }
    __syncthreads();
    if (j >= H_) return;
    const float4* h4p = (const float4*)nod_s[r];
    float wa = 0.f;
#pragma unroll 5
    for (int k4 = 0; k4 < 25; ++k4) {
        const float4 h4 = h4p[k4];
        const int k = k4 * 4;
        wa = fmaf(h4.x, Ww[(k + 0) * H_ + j], wa);
        wa = fmaf(h4.y, Ww[(k + 1) * H_ + j], wa);
        wa = fmaf(h4.z, Ww[(k + 2) * H_ + j], wa);
        wa = fmaf(h4.w, Ww[(k + 3) * H_ + j], wa);
    }
    hw[(size_t)(row0 + r) * H_ + j] = wa;
}

// ---------------------------------------------------------------------------
// K2 (r7): r0 message-loop structure (e_s LDS b128 broadcast, global hww,
// direct weight loads, batch-affine swizzle) + 2-ROW REGISTER TILING.
// Model fitting r0-r6: VALU issue is ~22 us in every variant; the ~30 us
// stall is aggregate L1/LDS BYTES (weights dominate: ~17 waves x 600 loads
// x 256 B = 2.6 MB/CU/pass), which relocation (r2/r3/r5) cannot reduce.
// r1 proved 4x byte-cut works (issue fell) but died at 8 waves/CU w/o
// swizzle. This version: 2 rows/thread, 4 rows/block, grid 1024 =
// 4 blocks/CU = 16 waves/CU, swizzle kept -> every weight and hww load
// feeds 2 FMAs: bytes/CU halve at near-constant occupancy.
template <int MODE, int INIT_HV>
__global__ __launch_bounds__(256, 6) void k_pass(const float* __restrict__ edges,
                                                 const float* __restrict__ We,
                                                 const float* __restrict__ Wu,
                                                 const float* __restrict__ Wv,
                                                 const float* __restrict__ Ww,
                                                 const float* __restrict__ Wr,
                                                 const float* __restrict__ nodes,
                                                 float* __restrict__ hv_io,
                                                 const float* __restrict__ hw_in,
                                                 float* __restrict__ hw_out,
                                                 const float* __restrict__ hid_in,
                                                 float* __restrict__ hidden,
                                                 float* __restrict__ out) {
    __shared__ float4 e_s[4][N_];          // 8 KB
    __shared__ float  asum_s[4][2];        // per-half-row edge sums
    __shared__ unsigned qmask_s[4][4];     // per-row edge-mask bits (4x32)
    __shared__ float  hid_s[4][H_];
    __shared__ float  msg_s[4][H_];
    __shared__ float  hn_s[4][H_];
    __shared__ float  nod_s[4][H_];        // MODE 2 only
    __shared__ float  red_s[4][H_];        // MODE 2 only

    // batch-affine swizzle: co-resident blocks (≡ mod 256) share batch b
    const int bx = blockIdx.x;             // grid = 1024
    const int cu = bx & 255, slot = bx >> 8;    // slot 0..3
    const int b = cu >> 3;
    const int vt = (cu & 7) + slot * 8;    // 0..31 (32 tiles x 4 rows)
    const int row0 = b * N_ + vt * 4;

    const int t = threadIdx.x, rg = t >> 7, j = t & 127;
    const int wv = t >> 6, lane = t & 63;
    const int ra = rg * 2, rb = ra + 1;    // this thread's two rows
    const int rowA = row0 + ra, rowB = row0 + rb;
    const bool act = (j < H_);

    {   // stage 4 rows' edges (512 float4); ballot masks; half-row sums
        const float4* eg = (const float4*)(edges + (size_t)row0 * N_ * 4);
        float4* es = &e_s[0][0];
#pragma unroll
        for (int q = 0; q < 2; ++q) {
            const int idx = q * 256 + t;          // coalesced
            const float4 e = eg[idx];
            es[idx] = e;
            float s = (e.x + e.y) + (e.z + e.w);
            const unsigned long long bal = __ballot(s != 0.f);
            const int seg = q * 4 + wv;           // half-row id (wave-uniform)
            const int rowq = seg >> 1, half = seg & 1;
            if (lane == 0) {
                qmask_s[rowq][half * 2]     = (unsigned)bal;
                qmask_s[rowq][half * 2 + 1] = (unsigned)(bal >> 32);
            }
#pragma unroll
            for (int off = 32; off > 0; off >>= 1) s += __shfl_down(s, off);
            if (lane == 0) asum_s[rowq][half] = s;
        }
    }
    {   // stage pre-update hidden rows (4 x 25 float4); nodes too if readout
        const float4* hg = (const float4*)(hid_in + (size_t)row0 * H_);
        if (t < 100) ((float4*)hid_s)[t] = hg[t];
        if (MODE == 2) {
            const float4* ng = (const float4*)(nodes + (size_t)row0 * H_);
            if (t < 100) ((float4*)nod_s)[t] = ng[t];
        }
    }
    __syncthreads();

    const float nmA = ((asum_s[ra][0] + asum_s[ra][1]) != 0.f) ? 1.f : 0.f;
    const float nmB = ((asum_s[rb][0] + asum_s[rb][1]) != 0.f) ? 1.f : 0.f;

    if (act) {
        float hvA, hvB;
        if (INIT_HV) {      // pass 1: hv = hid @ Wv, weight loads shared
            const float4* hA = (const float4*)hid_s[ra];
            const float4* hB = (const float4*)hid_s[rb];
            float vA = 0.f, vB = 0.f;
#pragma unroll 5
            for (int k4 = 0; k4 < 25; ++k4) {
                const int k = k4 * 4;
                const float w0 = Wv[(k + 0) * H_ + j];
                const float w1 = Wv[(k + 1) * H_ + j];
                const float w2 = Wv[(k + 2) * H_ + j];
                const float w3 = Wv[(k + 3) * H_ + j];
                const float4 a = hA[k4], c = hB[k4];
                vA = fmaf(a.x, w0, vA); vB = fmaf(c.x, w0, vB);
                vA = fmaf(a.y, w1, vA); vB = fmaf(c.y, w1, vB);
                vA = fmaf(a.z, w2, vA); vB = fmaf(c.z, w2, vB);
                vA = fmaf(a.w, w3, vA); vB = fmaf(c.w, w3, vB);
            }
            hvA = vA; hvB = vB;
        } else {
            hvA = hv_io[(size_t)rowA * H_ + j];
            hvB = hv_io[(size_t)rowB * H_ + j];
        }
        const float we0 = We[0 * H_ + j], we1 = We[1 * H_ + j];
        const float we2 = We[2 * H_ + j], we3 = We[3 * H_ + j];
        const float* hwp = hw_in + (size_t)b * N_ * H_ + j;
        float accA = 0.f, accB = 0.f;
        for (int c = 0; c < 4; ++c) {             // 4 chunks of 32 w
            const unsigned mqA =
                __builtin_amdgcn_readfirstlane(qmask_s[ra][c]);
            const unsigned mqB =
                __builtin_amdgcn_readfirstlane(qmask_s[rb][c]);
            const float4* ecA = &e_s[ra][c * 32];
            const float4* ecB = &e_s[rb][c * 32];
            const float*  hc  = hwp + (size_t)(c * 32) * H_;
#pragma unroll 8
            for (int w8 = 0; w8 < 32; ++w8) {
                const float hww = hc[w8 * H_];    // 1 global load, 2 rows
                const float4 eA = ecA[w8];        // LDS b128 broadcast
                const float4 eB = ecB[w8];
                float pA = hvA + hww;
                pA = fmaf(eA.x, we0, pA);
                pA = fmaf(eA.y, we1, pA);
                pA = fmaf(eA.z, we2, pA);
                pA = fmaf(eA.w, we3, pA);
                const float mA = ((mqA >> w8) & 1u) ? 1.f : 0.f;
                accA = fmaf(mA, fmaxf(pA, 0.f), accA);
                float pB = hvB + hww;
                pB = fmaf(eB.x, we0, pB);
                pB = fmaf(eB.y, we1, pB);
                pB = fmaf(eB.z, we2, pB);
                pB = fmaf(eB.w, we3, pB);
                const float mB = ((mqB >> w8) & 1u) ? 1.f : 0.f;
                accB = fmaf(mB, fmaxf(pB, 0.f), accB);
            }
        }
        msg_s[ra][j] = accA;
        msg_s[rb][j] = accB;
    }
    __syncthreads();

    float nhA, nhB;
    if (act) {
        const float4* hA = (const float4*)hid_s[ra];
        const float4* hB = (const float4*)hid_s[rb];
        const float4* mA4 = (const float4*)msg_s[ra];
        const float4* mB4 = (const float4*)msg_s[rb];
        float uA = 0.f, uB = 0.f;
#pragma unroll 5
        for (int k4 = 0; k4 < 25; ++k4) {
            const int k = k4 * 4;
            const float w0 = Wu[(k + 0) * H_ + j];
            const float w1 = Wu[(k + 1) * H_ + j];
            const float w2 = Wu[(k + 2) * H_ + j];
            const float w3 = Wu[(k + 3) * H_ + j];
            const float4 a = hA[k4], c = hB[k4];
            uA = fmaf(a.x, w0, uA); uB = fmaf(c.x, w0, uB);
            uA = fmaf(a.y, w1, uA); uB = fmaf(c.y, w1, uB);
            uA = fmaf(a.z, w2, uA); uB = fmaf(c.z, w2, uB);
            uA = fmaf(a.w, w3, uA); uB = fmaf(c.w, w3, uB);
        }
#pragma unroll 5
        for (int k4 = 0; k4 < 25; ++k4) {
            const int k = H_ + k4 * 4;
            const float w0 = Wu[(k + 0) * H_ + j];
            const float w1 = Wu[(k + 1) * H_ + j];
            const float w2 = Wu[(k + 2) * H_ + j];
            const float w3 = Wu[(k + 3) * H_ + j];
            const float4 a = mA4[k4], c = mB4[k4];
            uA = fmaf(a.x, w0, uA); uB = fmaf(c.x, w0, uB);
            uA = fmaf(a.y, w1, uA); uB = fmaf(c.y, w1, uB);
            uA = fmaf(a.z, w2, uA); uB = fmaf(c.z, w2, uB);
            uA = fmaf(a.w, w3, uA); uB = fmaf(c.w, w3, uB);
        }
        nhA = (nmA != 0.f) ? tanhf(uA) : hid_s[ra][j];
        nhB = (nmB != 0.f) ? tanhf(uB) : hid_s[rb][j];
        hn_s[ra][j] = nhA;
        hn_s[rb][j] = nhB;
        if (MODE == 1) {
            hidden[(size_t)rowA * H_ + j] = nhA;
            hidden[(size_t)rowB * H_ + j] = nhB;
        }
    }
    __syncthreads();

    if (MODE == 1) {        // next pass's hv/hw from fresh hidden (own rows)
        if (act) {
            const float4* hA = (const float4*)hn_s[ra];
            const float4* hB = (const float4*)hn_s[rb];
            float vA = 0.f, wA = 0.f, vB = 0.f, wB = 0.f;
#pragma unroll 5
            for (int k4 = 0; k4 < 25; ++k4) {
                const int k = k4 * 4;
                const float v0 = Wv[(k + 0) * H_ + j], q0 = Ww[(k + 0) * H_ + j];
                const float v1 = Wv[(k + 1) * H_ + j], q1 = Ww[(k + 1) * H_ + j];
                const float v2 = Wv[(k + 2) * H_ + j], q2 = Ww[(k + 2) * H_ + j];
                const float v3 = Wv[(k + 3) * H_ + j], q3 = Ww[(k + 3) * H_ + j];
                const float4 a = hA[k4], c = hB[k4];
                vA = fmaf(a.x, v0, vA); wA = fmaf(a.x, q0, wA);
                vB = fmaf(c.x, v0, vB); wB = fmaf(c.x, q0, wB);
                vA = fmaf(a.y, v1, vA); wA = fmaf(a.y, q1, wA);
                vB = fmaf(c.y, v1, vB); wB = fmaf(c.y, q1, wB);
                vA = fmaf(a.z, v2, vA); wA = fmaf(a.z, q2, wA);
                vB = fmaf(c.z, v2, vB); wB = fmaf(c.z, q2, wB);
                vA = fmaf(a.w, v3, vA); wA = fmaf(a.w, q3, wA);
                vB = fmaf(c.w, v3, vB); wB = fmaf(c.w, q3, wB);
            }
            hv_io[(size_t)rowA * H_ + j] = vA;    // row-local: safe in-place
            hv_io[(size_t)rowB * H_ + j] = vB;
            hw_out[(size_t)rowA * H_ + j] = wA;   // double-buffered
            hw_out[(size_t)rowB * H_ + j] = wB;
        }
    } else {                // MODE 2: fused readout, Wr loads shared
        if (act) {
            const float4* hA = (const float4*)hn_s[ra];
            const float4* hB = (const float4*)hn_s[rb];
            const float4* nA = (const float4*)nod_s[ra];
            const float4* nB = (const float4*)nod_s[rb];
            float uA = 0.f, uB = 0.f;
#pragma unroll 5
            for (int k4 = 0; k4 < 25; ++k4) {
                const int k = k4 * 4;
                const float w0 = Wr[(k + 0) * H_ + j];
                const float w1 = Wr[(k + 1) * H_ + j];
                const float w2 = Wr[(k + 2) * H_ + j];
                const float w3 = Wr[(k + 3) * H_ + j];
                const float4 a = hA[k4], c = hB[k4];
                uA = fmaf(a.x, w0, uA); uB = fmaf(c.x, w0, uB);
                uA = fmaf(a.y, w1, uA); uB = fmaf(c.y, w1, uB);
                uA = fmaf(a.z, w2, uA); uB = fmaf(c.z, w2, uB);
                uA = fmaf(a.w, w3, uA); uB = fmaf(c.w, w3, uB);
            }
#pragma unroll 5
            for (int k4 = 0; k4 < 25; ++k4) {
                const int k = H_ + k4 * 4;
                const float w0 = Wr[(k + 0) * H_ + j];
                const float w1 = Wr[(k + 1) * H_ + j];
                const float w2 = Wr[(k + 2) * H_ + j];
                const float w3 = Wr[(k + 3) * H_ + j];
                const float4 a = nA[k4], c = nB[k4];
                uA = fmaf(a.x, w0, uA); uB = fmaf(c.x, w0, uB);
                uA = fmaf(a.y, w1, uA); uB = fmaf(c.y, w1, uB);
                uA = fmaf(a.z, w2, uA); uB = fmaf(c.z, w2, uB);
                uA = fmaf(a.w, w3, uA); uB = fmaf(c.w, w3, uB);
            }
            red_s[ra][j] = nmA * fmaxf(uA, 0.f);
            red_s[rb][j] = nmB * fmaxf(uB, 0.f);
        }
        __syncthreads();
        if (t < H_) {
            const float ssum = (red_s[0][t] + red_s[1][t]) +
                               (red_s[2][t] + red_s[3][t]);
            atomicAdd(out + b * H_ + t, ssum);
        }
    }
}

// ---------------------------------------------------------------------------
extern "C" void kernel_launch(void* const* d_in, const int* in_sizes, int n_in,
                              void* d_out, int out_size, void* d_ws, size_t ws_size,
                              hipStream_t stream) {
    const float* nodes = (const float*)d_in[0];
    const float* edges = (const float*)d_in[1];
    const float* Wv    = (const float*)d_in[2];
    const float* Ww    = (const float*)d_in[3];
    const float* We    = (const float*)d_in[4];
    const float* Wu    = (const float*)d_in[5];
    const float* Wr    = (const float*)d_in[6];
    float* out = (float*)d_out;

    float* hidden = (float*)d_ws;     // RH
    float* hv     = hidden + RH;      // RH
    float* hwA    = hv + RH;          // RH
    float* hwB    = hwA + RH;         // RH

    k_proj0<<<ROWS / 2, 256, 0, stream>>>(nodes, Ww, hwA, out);

    k_pass<1, 1><<<ROWS / 4, 256, 0, stream>>>(edges, We, Wu, Wv, Ww, Wr, nodes,
                                               hv, hwA, hwB, nodes, hidden, out);
    k_pass<1, 0><<<ROWS / 4, 256, 0, stream>>>(edges, We, Wu, Wv, Ww, Wr, nodes,
                                               hv, hwB, hwA, hidden, hidden, out);
    k_pass<2, 0><<<ROWS / 4, 256, 0, stream>>>(edges, We, Wu, Wv, Ww, Wr, nodes,
                                               hv, hwA, hwB, hidden, hidden, out);
}